// Round 1
// baseline (568.993 us; speedup 1.0000x reference)
//
#include <hip/hip_runtime.h>
#include <math.h>

#define NB 8
#define IC 256
#define CC 64
#define HH 128
#define WW 128
#define NN (HH*WW)      // 16384
#define NKW 32          // k-chunks for gram W (8192/32 = 256 rows each)
#define NKC 32          // n-chunks for gram C (16384/32 = 512 cols each)

// ---------------- workspace layout (floats) ----------------
static constexpr size_t SZ_INP = (size_t)NB * CC * NN;          // 8,388,608
static constexpr size_t OFF_INP = 0;
static constexpr size_t OFF_S   = OFF_INP + SZ_INP;             // s buffer, same size
static constexpr size_t OFF_PW  = OFF_S + SZ_INP;
static constexpr size_t SZ_PW   = (size_t)NB * NKW * 16384;     // 4,194,304
static constexpr size_t OFF_PC  = OFF_PW + SZ_PW;
static constexpr size_t SZ_PC   = (size_t)NB * NKC * 4096;      // 1,048,576
static constexpr size_t OFF_TW  = OFF_PC + SZ_PC;
static constexpr size_t OFF_TC  = OFF_TW + (size_t)NB * 16384;
// total = 22,183,936 floats = ~88.7 MB

// ---------------- inconv: inp[b,o,n] = sum_i w_in[o,i]*x[b,i,n] + b_in[o] ----------------
// grid (NN/64, NB), block 256 = 16(tx: n, 4 each) x 16(ty: o, 4 each) -> covers 64 o x 64 n
__global__ __launch_bounds__(256) void k_inconv(
    const float* __restrict__ x, const float* __restrict__ w_in,
    const float* __restrict__ b_in, float* __restrict__ inp)
{
    __shared__ float wl[CC * IC];   // direct copy of w_in [o][i], 64 KB
    __shared__ float xs[64 * 64];   // x tile [i_local][n_local], 16 KB
    const int b  = blockIdx.y;
    const int n0 = blockIdx.x * 64;
    const int t  = threadIdx.x;
    const int tx = t & 15, ty = t >> 4;

    for (int idx = t; idx < CC * IC; idx += 256) wl[idx] = w_in[idx];

    float acc[4][4];
#pragma unroll
    for (int a = 0; a < 4; a++)
#pragma unroll
        for (int j = 0; j < 4; j++) acc[a][j] = 0.f;

    const int sr = t >> 2, sq = t & 3;
    for (int ic0 = 0; ic0 < IC; ic0 += 64) {
        __syncthreads();
        {
            const float* src = x + ((size_t)b * IC + ic0 + sr) * NN + n0 + sq * 16;
            float* dst = xs + sr * 64 + sq * 16;
#pragma unroll
            for (int k = 0; k < 4; k++)
                *(float4*)(dst + 4 * k) = *(const float4*)(src + 4 * k);
        }
        __syncthreads();
#pragma unroll 8
        for (int i = 0; i < 64; i++) {
            float4 xv = *(const float4*)(xs + i * 64 + tx * 4);
            const int ic = ic0 + i;
            float w0 = wl[(ty * 4 + 0) * IC + ic];
            float w1 = wl[(ty * 4 + 1) * IC + ic];
            float w2 = wl[(ty * 4 + 2) * IC + ic];
            float w3 = wl[(ty * 4 + 3) * IC + ic];
            acc[0][0] += w0 * xv.x; acc[0][1] += w0 * xv.y; acc[0][2] += w0 * xv.z; acc[0][3] += w0 * xv.w;
            acc[1][0] += w1 * xv.x; acc[1][1] += w1 * xv.y; acc[1][2] += w1 * xv.z; acc[1][3] += w1 * xv.w;
            acc[2][0] += w2 * xv.x; acc[2][1] += w2 * xv.y; acc[2][2] += w2 * xv.z; acc[2][3] += w2 * xv.w;
            acc[3][0] += w3 * xv.x; acc[3][1] += w3 * xv.y; acc[3][2] += w3 * xv.z; acc[3][3] += w3 * xv.w;
        }
    }
#pragma unroll
    for (int a = 0; a < 4; a++) {
        const int o = ty * 4 + a;
        const float bo = b_in[o];
        float4 v = make_float4(acc[a][0] + bo, acc[a][1] + bo, acc[a][2] + bo, acc[a][3] + bo);
        *(float4*)(inp + ((size_t)b * CC + o) * NN + n0 + tx * 4) = v;
    }
}

// ---------------- gram W partials: S[w,v] = sum_k Xw[k,w]*Xw[k,v], Xw = inp[b] as [8192][128] ----------------
// grid (NKW, NB), block 256 = 16x16, thread tile 8x8 of the 128x128 output
__global__ __launch_bounds__(256) void k_gramW(const float* __restrict__ inp, float* __restrict__ pW)
{
    __shared__ float xs[8 * 128];   // 8 k-rows, 4 KB
    const int b = blockIdx.y, kc = blockIdx.x;
    const int t = threadIdx.x, tx = t & 15, ty = t >> 4;
    const float* Xb = inp + (size_t)b * CC * NN;
    const int k0 = kc * ((CC * HH) / NKW);   // 256 rows per chunk

    float acc[8][8];
#pragma unroll
    for (int i = 0; i < 8; i++)
#pragma unroll
        for (int j = 0; j < 8; j++) acc[i][j] = 0.f;

    for (int kk = k0; kk < k0 + 256; kk += 8) {
        __syncthreads();
        for (int idx = t; idx < 1024; idx += 256)
            xs[idx] = Xb[((size_t)kk + (idx >> 7)) * WW + (idx & 127)];
        __syncthreads();
#pragma unroll
        for (int k = 0; k < 8; k++) {
            const float* row = xs + k * 128;
            float4 t0 = *(const float4*)(row + ty * 8);
            float4 t1 = *(const float4*)(row + ty * 8 + 4);
            float4 u0 = *(const float4*)(row + tx * 8);
            float4 u1 = *(const float4*)(row + tx * 8 + 4);
            float av[8] = {t0.x, t0.y, t0.z, t0.w, t1.x, t1.y, t1.z, t1.w};
            float bv[8] = {u0.x, u0.y, u0.z, u0.w, u1.x, u1.y, u1.z, u1.w};
#pragma unroll
            for (int i = 0; i < 8; i++)
#pragma unroll
                for (int j = 0; j < 8; j++) acc[i][j] += av[i] * bv[j];
        }
    }
    float* dst = pW + ((size_t)b * NKW + kc) * 16384;
#pragma unroll
    for (int i = 0; i < 8; i++) {
#pragma unroll
        for (int j = 0; j < 8; j += 4) {
            float4 v = make_float4(acc[i][j], acc[i][j + 1], acc[i][j + 2], acc[i][j + 3]);
            *(float4*)(dst + (ty * 8 + i) * 128 + tx * 8 + j) = v;
        }
    }
}

__global__ __launch_bounds__(256) void k_redW(const float* __restrict__ pW, float* __restrict__ Tw)
{
    const int b = blockIdx.y;
    const int idx = blockIdx.x * 256 + threadIdx.x;   // grid.x = 64 -> 16384
    const float* p = pW + (size_t)b * NKW * 16384 + idx;
    float acc = 0.f;
#pragma unroll
    for (int k = 0; k < NKW; k++) acc += p[(size_t)k * 16384];
    Tw[(size_t)b * 16384 + idx] = acc;
}

// softmax over rows w for each column v (axis=1 of [B,W,V]); in-place on Tw
__global__ __launch_bounds__(128) void k_softW(float* __restrict__ Tw)
{
    const int b = blockIdx.x, v = threadIdx.x;
    float* S = Tw + (size_t)b * 16384;
    float m = -3.4e38f;
    for (int w = 0; w < 128; w++) m = fmaxf(m, S[w * 128 + v]);
    float sum = 0.f;
    for (int w = 0; w < 128; w++) { float e = __expf(S[w * 128 + v] - m); sum += e; S[w * 128 + v] = e; }
    const float inv = 1.f / sum;
    for (int w = 0; w < 128; w++) S[w * 128 + v] *= inv;
}

// ---------------- gram C partials: G[c,d] = sum_n inp[b,c,n]*inp[b,d,n] ----------------
// grid (NKC, NB), block 256 = 16x16, thread tile 4x4 of the 64x64 output
__global__ __launch_bounds__(256) void k_gramC(const float* __restrict__ inp, float* __restrict__ pC)
{
    __shared__ float xs[64 * 33];   // [c][n-tile 32], padded to 33 to break bank collisions
    const int b = blockIdx.y, nc = blockIdx.x;
    const int t = threadIdx.x, tx = t & 15, ty = t >> 4;
    const float* ip = inp + (size_t)b * CC * NN;
    const int n0 = nc * (NN / NKC);   // 512

    float acc[4][4];
#pragma unroll
    for (int i = 0; i < 4; i++)
#pragma unroll
        for (int j = 0; j < 4; j++) acc[i][j] = 0.f;

    const int scc = t >> 2, sq = t & 3;
    for (int nt = 0; nt < NN / NKC; nt += 32) {
        __syncthreads();
        {
            const float* src = ip + (size_t)scc * NN + n0 + nt + sq * 8;
            float* dst = xs + scc * 33 + sq * 8;
#pragma unroll
            for (int k = 0; k < 8; k++) dst[k] = src[k];
        }
        __syncthreads();
#pragma unroll 4
        for (int nn = 0; nn < 32; nn++) {
            float a0 = xs[(ty * 4 + 0) * 33 + nn];
            float a1 = xs[(ty * 4 + 1) * 33 + nn];
            float a2 = xs[(ty * 4 + 2) * 33 + nn];
            float a3 = xs[(ty * 4 + 3) * 33 + nn];
            float e0 = xs[(tx * 4 + 0) * 33 + nn];
            float e1 = xs[(tx * 4 + 1) * 33 + nn];
            float e2 = xs[(tx * 4 + 2) * 33 + nn];
            float e3 = xs[(tx * 4 + 3) * 33 + nn];
            acc[0][0] += a0 * e0; acc[0][1] += a0 * e1; acc[0][2] += a0 * e2; acc[0][3] += a0 * e3;
            acc[1][0] += a1 * e0; acc[1][1] += a1 * e1; acc[1][2] += a1 * e2; acc[1][3] += a1 * e3;
            acc[2][0] += a2 * e0; acc[2][1] += a2 * e1; acc[2][2] += a2 * e2; acc[2][3] += a2 * e3;
            acc[3][0] += a3 * e0; acc[3][1] += a3 * e1; acc[3][2] += a3 * e2; acc[3][3] += a3 * e3;
        }
    }
    float* dst = pC + ((size_t)b * NKC + nc) * 4096;
#pragma unroll
    for (int i = 0; i < 4; i++) {
        float4 v = make_float4(acc[i][0], acc[i][1], acc[i][2], acc[i][3]);
        *(float4*)(dst + (ty * 4 + i) * 64 + tx * 4) = v;
    }
}

__global__ __launch_bounds__(256) void k_redC(const float* __restrict__ pC, float* __restrict__ Tc)
{
    const int b = blockIdx.y;
    const int idx = blockIdx.x * 256 + threadIdx.x;   // grid.x = 16 -> 4096
    const float* p = pC + (size_t)b * NKC * 4096 + idx;
    float acc = 0.f;
#pragma unroll
    for (int k = 0; k < NKC; k++) acc += p[(size_t)k * 4096];
    Tc[(size_t)b * 4096 + idx] = acc;
}

__global__ __launch_bounds__(64) void k_softC(float* __restrict__ Tc)
{
    const int b = blockIdx.x, d = threadIdx.x;
    float* S = Tc + (size_t)b * 4096;
    float m = -3.4e38f;
    for (int c = 0; c < 64; c++) m = fmaxf(m, S[c * 64 + d]);
    float sum = 0.f;
    for (int c = 0; c < 64; c++) { float e = __expf(S[c * 64 + d] - m); sum += e; S[c * 64 + d] = e; }
    const float inv = 1.f / sum;
    for (int c = 0; c < 64; c++) S[c * 64 + d] *= inv;
}

// ---------------- Co: s_flat[b][n*64+d] = detal * sum_c inp[b,c,n]*Tc[c,d] ----------------
// (the "scrambled" reshape of Co to [C,H,W] is exactly this flat layout)
// grid (NN/256, NB), block 256; thread t owns column n
__global__ __launch_bounds__(256) void k_co(
    const float* __restrict__ inp, const float* __restrict__ Tc,
    const float* __restrict__ detal, float* __restrict__ s)
{
    __shared__ float tc[64 * 64];   // 16 KB
    const int b = blockIdx.y;
    const int t = threadIdx.x;
    const int n = blockIdx.x * 256 + t;
    for (int idx = t; idx < 4096; idx += 256) tc[idx] = Tc[(size_t)b * 4096 + idx];
    __syncthreads();

    float acc[64];
#pragma unroll
    for (int d = 0; d < 64; d++) acc[d] = 0.f;

    const float* ip = inp + (size_t)b * CC * NN + n;
    for (int c = 0; c < 64; c++) {
        const float xv = ip[(size_t)c * NN];
        const float* tr = tc + c * 64;
#pragma unroll
        for (int d = 0; d < 64; d += 4) {
            float4 w4 = *(const float4*)(tr + d);
            acc[d + 0] += xv * w4.x; acc[d + 1] += xv * w4.y;
            acc[d + 2] += xv * w4.z; acc[d + 3] += xv * w4.w;
        }
    }
    const float sc = detal[0];
    float* sp = s + (size_t)b * CC * NN + (size_t)n * 64;
#pragma unroll
    for (int d = 0; d < 64; d += 4) {
        float4 v = make_float4(acc[d] * sc, acc[d + 1] * sc, acc[d + 2] * sc, acc[d + 3] * sc);
        *(float4*)(sp + d) = v;
    }
}

// ---------------- Wo (== Ho): s[b,c,h,v] += 2*detal * sum_w inp[b,c,h,w]*Tw[w,v] ----------------
// grid (CC, NB), block 256; Tw staged in LDS (64 KB), 32 rows staged per pass
__global__ __launch_bounds__(256) void k_wo(
    const float* __restrict__ inp, const float* __restrict__ Tw,
    const float* __restrict__ detal, float* __restrict__ s)
{
    __shared__ float tw[128 * 128];   // 64 KB [w][v]
    __shared__ float rs[32 * 128];    // 16 KB staged rows [r][w]
    const int b = blockIdx.y, c = blockIdx.x;
    const int t = threadIdx.x;
    const int v4 = (t & 31) * 4;      // 32 v-threads x 4
    const int rg = t >> 5;            // 8 row groups x 4 rows

    const float* twg = Tw + (size_t)b * 16384;
    for (int idx = t * 4; idx < 16384; idx += 1024)
        *(float4*)(tw + idx) = *(const float4*)(twg + idx);

    const float* ip = inp + ((size_t)b * CC + c) * NN;
    float* sp = s + ((size_t)b * CC + c) * NN;
    const float sc2 = 2.0f * detal[0];
    const int sr = t >> 3, sq = t & 7;

    for (int h0 = 0; h0 < HH; h0 += 32) {
        __syncthreads();
        {
            const float* src = ip + (size_t)(h0 + sr) * WW + sq * 16;
            float* dst = rs + sr * 128 + sq * 16;
#pragma unroll
            for (int k = 0; k < 4; k++)
                *(float4*)(dst + 4 * k) = *(const float4*)(src + 4 * k);
        }
        __syncthreads();

        float acc[4][4];
#pragma unroll
        for (int i = 0; i < 4; i++)
#pragma unroll
            for (int j = 0; j < 4; j++) acc[i][j] = 0.f;

#pragma unroll 2
        for (int w = 0; w < 128; w++) {
            float4 tv = *(const float4*)(tw + w * 128 + v4);
#pragma unroll
            for (int i = 0; i < 4; i++) {
                float a = rs[(rg * 4 + i) * 128 + w];
                acc[i][0] += a * tv.x; acc[i][1] += a * tv.y;
                acc[i][2] += a * tv.z; acc[i][3] += a * tv.w;
            }
        }
#pragma unroll
        for (int i = 0; i < 4; i++) {
            const int h = h0 + rg * 4 + i;
            float* p = sp + (size_t)h * WW + v4;
            float4 cur = *(const float4*)p;
            cur.x += sc2 * acc[i][0]; cur.y += sc2 * acc[i][1];
            cur.z += sc2 * acc[i][2]; cur.w += sc2 * acc[i][3];
            *(float4*)p = cur;
        }
    }
}

// ---------------- outconv: out[b,o,n] = sum_c w_out[o,c]*s[b,c,n] + b_out[o] + x[b,o,n] ----------------
// grid (NN/64, NB), block 256 = 16(tx: n, 4 each) x 16(ty: o, 16 each)
__global__ __launch_bounds__(256) void k_outconv(
    const float* __restrict__ s, const float* __restrict__ w_out,
    const float* __restrict__ b_out, const float* __restrict__ x,
    float* __restrict__ outp)
{
    __shared__ float wl[IC * CC];   // 64 KB direct copy [o][c]
    __shared__ float ss[64 * 64];   // 16 KB s tile [c][n]
    const int b  = blockIdx.y;
    const int n0 = blockIdx.x * 64;
    const int t  = threadIdx.x, tx = t & 15, ty = t >> 4;

    for (int idx = t; idx < IC * CC; idx += 256) wl[idx] = w_out[idx];
    {
        const int r = t >> 2, q = t & 3;
        const float* src = s + ((size_t)b * CC + r) * NN + n0 + q * 16;
        float* dst = ss + r * 64 + q * 16;
#pragma unroll
        for (int k = 0; k < 4; k++)
            *(float4*)(dst + 4 * k) = *(const float4*)(src + 4 * k);
    }
    __syncthreads();

    float acc[16][4];
#pragma unroll
    for (int a = 0; a < 16; a++)
#pragma unroll
        for (int j = 0; j < 4; j++) acc[a][j] = 0.f;

#pragma unroll 4
    for (int cc = 0; cc < 64; cc++) {
        float4 sv = *(const float4*)(ss + cc * 64 + tx * 4);
#pragma unroll
        for (int a = 0; a < 16; a++) {
            float w = wl[(ty * 16 + a) * CC + cc];
            acc[a][0] += w * sv.x; acc[a][1] += w * sv.y;
            acc[a][2] += w * sv.z; acc[a][3] += w * sv.w;
        }
    }

    const float* xb = x + (size_t)b * IC * NN + n0 + tx * 4;
    float* ob = outp + (size_t)b * IC * NN + n0 + tx * 4;
#pragma unroll
    for (int a = 0; a < 16; a++) {
        const int o = ty * 16 + a;
        const float bo = b_out[o];
        float4 xv = *(const float4*)(xb + (size_t)o * NN);
        float4 v = make_float4(acc[a][0] + bo + xv.x, acc[a][1] + bo + xv.y,
                               acc[a][2] + bo + xv.z, acc[a][3] + bo + xv.w);
        *(float4*)(ob + (size_t)o * NN) = v;
    }
}

extern "C" void kernel_launch(void* const* d_in, const int* in_sizes, int n_in,
                              void* d_out, int out_size, void* d_ws, size_t ws_size,
                              hipStream_t stream)
{
    const float* x     = (const float*)d_in[0];
    const float* w_in  = (const float*)d_in[1];
    const float* b_in  = (const float*)d_in[2];
    const float* w_out = (const float*)d_in[3];
    const float* b_out = (const float*)d_in[4];
    const float* detal = (const float*)d_in[5];
    float* out = (float*)d_out;

    float* ws  = (float*)d_ws;
    float* inp = ws + OFF_INP;
    float* s   = ws + OFF_S;
    float* pW  = ws + OFF_PW;
    float* pC  = ws + OFF_PC;
    float* Tw  = ws + OFF_TW;
    float* Tc  = ws + OFF_TC;

    k_inconv <<<dim3(NN / 64, NB), 256, 0, stream>>>(x, w_in, b_in, inp);
    k_gramW  <<<dim3(NKW, NB),     256, 0, stream>>>(inp, pW);
    k_redW   <<<dim3(64, NB),      256, 0, stream>>>(pW, Tw);
    k_softW  <<<dim3(NB),          128, 0, stream>>>(Tw);
    k_gramC  <<<dim3(NKC, NB),     256, 0, stream>>>(inp, pC);
    k_redC   <<<dim3(16, NB),      256, 0, stream>>>(pC, Tc);
    k_softC  <<<dim3(NB),           64, 0, stream>>>(Tc);
    k_co     <<<dim3(NN / 256, NB), 256, 0, stream>>>(inp, Tc, detal, s);
    k_wo     <<<dim3(CC, NB),      256, 0, stream>>>(inp, Tw, detal, s);
    k_outconv<<<dim3(NN / 64, NB), 256, 0, stream>>>(s, w_out, b_out, x, out);
}